// Round 5
// baseline (565.295 us; speedup 1.0000x reference)
//
#include <hip/hip_runtime.h>
#include <hip/hip_bf16.h>

#define M 2048
#define N 131072
#define D 256

#define QT 128      // q-rows per block
#define NT 128      // n-cols per block (4 waves x 32)
#define QPAD 136    // 128 + 8 halves row stride: conflict-free b128 LDS reads/writes

typedef __attribute__((ext_vector_type(8))) _Float16 half8;  // 8 f16 (4 VGPRs)
typedef __attribute__((ext_vector_type(8))) short short8;
typedef __attribute__((ext_vector_type(4))) float f32x4;     // MFMA acc
typedef unsigned long long ull;

__device__ __forceinline__ ull pack_key(float score, unsigned idx) {
    unsigned u = __float_as_uint(score);
    u = (u & 0x80000000u) ? ~u : (u | 0x80000000u);   // monotonic total order
    return ((ull)u << 32) | idx;
}
__device__ __forceinline__ ull shfl_xor_u64_w16(ull x, int mask) {
    unsigned lo = (unsigned)x, hi = (unsigned)(x >> 32);
    lo = (unsigned)__shfl_xor((int)lo, mask, 16);
    hi = (unsigned)__shfl_xor((int)hi, mask, 16);
    return ((ull)hi << 32) | lo;
}

// ---------------- Kernel A1: V -> f16 in FRAGMENT-LINEAR layout + vsq ----------------
// Layout: for n-group g=n>>4 and chunk c=k>>5, a 1KB tile of 512 halves at
// vh[(g*8+c)*512], ordered so that lane l=quad*16+tx holds row n=g*16+tx,
// k=c*32+quad*8..+7 -> a wave's B-frag load is one contiguous 1KB access.
__global__ __launch_bounds__(256) void convert_v_swz(const float* __restrict__ v,
                                                     short* __restrict__ vh,
                                                     float* __restrict__ vsq) {
    __shared__ float part[4][16];
    const int g    = blockIdx.x;        // n-group, N/16 = 8192
    const int t    = threadIdx.x;
    const int w    = t >> 6;
    const int l    = t & 63;
    const int quad = (t >> 4) & 3;
    const int tx   = t & 15;

    float s = 0.f;
#pragma unroll
    for (int h = 0; h < 2; ++h) {
        const int c = w + h * 4;        // wave w handles chunks {w, w+4}
        const float* src = v + (size_t)(g * 16 + tx) * D + c * 32 + quad * 8;
        float tmp[8] __attribute__((aligned(16)));
        *(float4*)&tmp[0] = *(const float4*)src;
        *(float4*)&tmp[4] = *(const float4*)(src + 4);
        half8 hh;
#pragma unroll
        for (int e = 0; e < 8; ++e) {
            hh[e] = (_Float16)tmp[e];   // RNE f32->f16
            s += tmp[e] * tmp[e];
        }
        // per wave: contiguous 1KB write (lane l at +16B*l)
        *(short8*)(vh + ((size_t)g * 8 + c) * 512 + l * 8) = *(short8*)&hh;
    }
    // row-sum: lanes l, l^16, l^32, l^48 share row tx
    s += __shfl_xor(s, 16, 64);
    s += __shfl_xor(s, 32, 64);
    if (l < 16) part[w][l] = s;
    __syncthreads();
    if (t < 16) vsq[g * 16 + t] = part[0][t] + part[1][t] + part[2][t] + part[3][t];
}

// ---------------- Kernel A2: Q -> f16 row-major + key init ----------------
__global__ __launch_bounds__(256) void convert_q_kernel(const float* __restrict__ q,
                                                        short* __restrict__ qh,
                                                        ull* __restrict__ keys) {
    const size_t t = (size_t)blockIdx.x * 256 + threadIdx.x;   // M*D/8 threads
    const float* src = q + t * 8;
    float tmp[8] __attribute__((aligned(16)));
    *(float4*)&tmp[0] = *(const float4*)src;
    *(float4*)&tmp[4] = *(const float4*)(src + 4);
    half8 h;
#pragma unroll
    for (int e = 0; e < 8; ++e) h[e] = (_Float16)tmp[e];
    *(short8*)(qh + t * 8) = *(short8*)&h;
    if (blockIdx.x == 0) {
        for (int i = threadIdx.x; i < 2 * M; i += 256) keys[i] = ~0ull;
    }
}

// ---------------- Kernel B: barrier-free-K-loop f16 MFMA + top-2 insert ----------------
// Wave tile 128q x 32n (waves split n). Q in LDS (2 half-D phases, padded);
// V B-frags loaded register-direct from the fragment-linear layout (no barrier).
__global__ __launch_bounds__(256) void dist_argmin_f16(const short* __restrict__ qh,
                                                       const short* __restrict__ vh,
                                                       const float* __restrict__ vsq,
                                                       ull* __restrict__ keys1,
                                                       ull* __restrict__ keys2) {
    __shared__ __align__(16) short sQ[QT * QPAD];   // 34,816 B
    __shared__ ull red[QT][4];

    const int tid  = threadIdx.x;
    const int lane = tid & 63;
    const int w    = tid >> 6;
    const int tx   = lane & 15;
    const int quad = lane >> 4;

    const int qb0 = blockIdx.x * QT;     // 16 q-blocks (x fastest: blocks sharing
    const int vb0 = blockIdx.y * NT;     //  a V-tile dispatch adjacently -> L2 reuse)
    const int gw  = (vb0 >> 4) + w * 2;  // wave's first n-group

    f32x4 acc[8][2];
#pragma unroll
    for (int i = 0; i < 8; ++i) {
        acc[i][0] = (f32x4){0.f, 0.f, 0.f, 0.f};
        acc[i][1] = (f32x4){0.f, 0.f, 0.f, 0.f};
    }

    const short* bb0 = vh + ((size_t)gw * 8) * 512 + lane * 8;       // contiguous 1KB/load
    const short* bb1 = vh + ((size_t)(gw + 1) * 8) * 512 + lane * 8;

#pragma unroll
    for (int ph = 0; ph < 2; ++ph) {
        if (ph) __syncthreads();          // previous phase's reads done
        // stage 128 rows x 128 halves of Q; global coalesced, LDS conflict-free
#pragma unroll
        for (int k = 0; k < 8; ++k) {
            const int j   = k * 256 + tid;
            const int row = j >> 4;
            const int col = j & 15;
            const short8 qv = *(const short8*)(qh + (size_t)(qb0 + row) * D + ph * 128 + col * 8);
            *(short8*)(sQ + row * QPAD + col * 8) = qv;
        }
        __syncthreads();

#pragma unroll
        for (int cc = 0; cc < 4; ++cc) {
            const int c = ph * 4 + cc;
            const half8 b0 = *(const half8*)(bb0 + (size_t)c * 512);
            const half8 b1 = *(const half8*)(bb1 + (size_t)c * 512);
#pragma unroll
            for (int mt = 0; mt < 8; ++mt) {
                const half8 a = *(const half8*)(sQ + (mt * 16 + tx) * QPAD + cc * 32 + quad * 8);
                acc[mt][0] = __builtin_amdgcn_mfma_f32_16x16x32_f16(a, b0, acc[mt][0], 0, 0, 0);
                acc[mt][1] = __builtin_amdgcn_mfma_f32_16x16x32_f16(a, b1, acc[mt][1], 0, 0, 0);
            }
        }
    }

    // Epilogue: score = vsq - 2*cross; per-wave width-16 reduce; cross-wave via LDS.
    float vsqr[2];
    vsqr[0] = vsq[vb0 + w * 32 + tx];
    vsqr[1] = vsq[vb0 + w * 32 + 16 + tx];

#pragma unroll
    for (int mt = 0; mt < 8; ++mt) {
#pragma unroll
        for (int r = 0; r < 4; ++r) {
            const int ql = mt * 16 + quad * 4 + r;
            ull best = ~0ull;
#pragma unroll
            for (int nt = 0; nt < 2; ++nt) {
                const float score = fmaf(-2.0f, acc[mt][nt][r], vsqr[nt]);
                const unsigned idx = (unsigned)(vb0 + w * 32 + nt * 16 + tx);
                const ull key = pack_key(score, idx);
                best = best < key ? best : key;
            }
#pragma unroll
            for (int off = 8; off; off >>= 1) {
                const ull o = shfl_xor_u64_w16(best, off);
                best = best < o ? best : o;
            }
            if (tx == 0) red[ql][w] = best;
        }
    }
    __syncthreads();

    if (tid < QT) {
        ull x = red[tid][0];
        const ull r1 = red[tid][1], r2 = red[tid][2], r3 = red[tid][3];
        x = x < r1 ? x : r1;
        x = x < r2 ? x : r2;
        x = x < r3 ? x : r3;                      // block-best for this query
        const int qg = qb0 + tid;
        const ull old = atomicMin(&keys1[qg], x);
        const ull loser = (x < old) ? old : x;
        if (loser != ~0ull) atomicMin(&keys2[qg], loser);
    }
}

// ---------------- Kernel C: exact fp32 rescore of approx top-2 ----------------
__global__ __launch_bounds__(256) void rescore_kernel(const float* __restrict__ q,
                                                      const float* __restrict__ v,
                                                      const ull* __restrict__ keys1,
                                                      const ull* __restrict__ keys2,
                                                      int* __restrict__ out) {
    const int qi   = blockIdx.x * 4 + (threadIdx.x >> 6);
    const int lane = threadIdx.x & 63;
    const float4 qv = *(const float4*)(q + (size_t)qi * D + lane * 4);
    ull best = ~0ull;
    ull cand[2];
    cand[0] = keys1[qi];
    cand[1] = keys2[qi];
#pragma unroll
    for (int c = 0; c < 2; ++c) {
        if (cand[c] == ~0ull) continue;
        const unsigned idx = (unsigned)cand[c];
        const float4 vv = *(const float4*)(v + (size_t)idx * D + lane * 4);
        float s1 = vv.x * vv.x + vv.y * vv.y + vv.z * vv.z + vv.w * vv.w;   // ||v||^2
        float s2 = qv.x * vv.x + qv.y * vv.y + qv.z * vv.z + qv.w * vv.w;   // q.v
#pragma unroll
        for (int off = 32; off; off >>= 1) {
            s1 += __shfl_xor(s1, off, 64);
            s2 += __shfl_xor(s2, off, 64);
        }
        const float dist = fmaf(-2.0f, s2, s1);
        const ull key = pack_key(dist, idx);
        best = best < key ? best : key;
    }
    if (lane == 0) out[qi] = (int)(unsigned)(best & 0xFFFFFFFFull);
}

extern "C" void kernel_launch(void* const* d_in, const int* in_sizes, int n_in,
                              void* d_out, int out_size, void* d_ws, size_t ws_size,
                              hipStream_t stream) {
    const float* q = (const float*)d_in[0];
    const float* v = (const float*)d_in[1];
    int* out = (int*)d_out;

    char* ws = (char*)d_ws;
    float* vsq = (float*)ws;                 ws += (size_t)N * sizeof(float);
    ull* keys1 = (ull*)ws;                   ws += (size_t)2 * M * sizeof(ull);
    ull* keys2 = keys1 + M;
    short* qh = (short*)ws;                  ws += (size_t)M * D * 2;
    short* vh = (short*)ws;                  // N*D*2 = 64 MB (ws >= 136 MB proven in r3)

    convert_v_swz<<<N / 16, 256, 0, stream>>>(v, vh, vsq);
    convert_q_kernel<<<((size_t)M * D / 8) / 256, 256, 0, stream>>>(q, qh, keys1);

    dim3 grid(M / QT, N / NT);   // (16, 1024): x fastest -> 16 blocks share a V-tile
    dist_argmin_f16<<<grid, 256, 0, stream>>>(qh, vh, vsq, keys1, keys2);

    rescore_kernel<<<M / 4, 256, 0, stream>>>(q, v, keys1, keys2, out);
}

// Round 6
// 366.745 us; speedup vs baseline: 1.5414x; 1.5414x over previous
//
#include <hip/hip_runtime.h>
#include <hip/hip_bf16.h>

#define M 2048
#define N 131072
#define D 256

#define SLICE_G 128                    // n-groups (of 16) per slice = 2048 n = 1 MB f16
#define NSLICE  (N / (SLICE_G * 16))   // 64

typedef __attribute__((ext_vector_type(8))) _Float16 half8;  // 8 f16 (4 VGPRs)
typedef __attribute__((ext_vector_type(8))) short short8;
typedef __attribute__((ext_vector_type(4))) float f32x4;     // MFMA acc
typedef unsigned long long ull;

__device__ __forceinline__ ull pack_key(float score, unsigned idx) {
    unsigned u = __float_as_uint(score);
    u = (u & 0x80000000u) ? ~u : (u | 0x80000000u);   // monotonic total order
    return ((ull)u << 32) | idx;
}
__device__ __forceinline__ ull shfl_xor_u64_w16(ull x, int mask) {
    unsigned lo = (unsigned)x, hi = (unsigned)(x >> 32);
    lo = (unsigned)__shfl_xor((int)lo, mask, 16);
    hi = (unsigned)__shfl_xor((int)hi, mask, 16);
    return ((ull)hi << 32) | lo;
}

// ---------------- Kernel A: X -> f16 FRAGMENT-LINEAR + row sumsq (r5-verified swizzle) ----
// For row-group g and chunk c (k=c*32..+31): 1KB tile at xf[(g*8+c)*512]; lane
// l=quad*16+tx holds row g*16+tx, k=c*32+quad*8..+7 (matches MFMA A/B frag order).
__global__ __launch_bounds__(256) void convert_swz(const float* __restrict__ x,
                                                   short* __restrict__ xf,
                                                   float* __restrict__ xsq,
                                                   ull* __restrict__ keys) {
    __shared__ float part[4][16];
    const int g    = blockIdx.x;
    const int t    = threadIdx.x;
    const int w    = t >> 6;
    const int l    = t & 63;
    const int quad = (t >> 4) & 3;
    const int tx   = t & 15;

    float s = 0.f;
#pragma unroll
    for (int h = 0; h < 2; ++h) {
        const int c = w + h * 4;
        const float* src = x + (size_t)(g * 16 + tx) * D + c * 32 + quad * 8;
        float tmp[8] __attribute__((aligned(16)));
        *(float4*)&tmp[0] = *(const float4*)src;
        *(float4*)&tmp[4] = *(const float4*)(src + 4);
        half8 hh;
#pragma unroll
        for (int e = 0; e < 8; ++e) {
            hh[e] = (_Float16)tmp[e];
            s += tmp[e] * tmp[e];
        }
        *(short8*)(xf + ((size_t)g * 8 + c) * 512 + l * 8) = *(short8*)&hh;
    }
    s += __shfl_xor(s, 16, 64);
    s += __shfl_xor(s, 32, 64);
    if (l < 16) part[w][l] = s;
    __syncthreads();
    if (t < 16) xsq[g * 16 + t] = part[0][t] + part[1][t] + part[2][t] + part[3][t];
    if (keys && blockIdx.x == 0) {
        for (int i = t; i < 2 * M; i += 256) keys[i] = ~0ull;
    }
}

// ---------------- Kernel B: register-resident f16 MFMA, barrier-free, LDS-free ----------
// Wave owns 32 q-rows (A-frags in VGPRs for all K=256). Streams one n-slice of V
// frag-linear with register ping-pong prefetch. Tracks per-slot running argmin.
__global__ __launch_bounds__(256) void dist_argmin_reg(const short* __restrict__ qf,
                                                       const short* __restrict__ vf,
                                                       const float* __restrict__ vsq,
                                                       ull* __restrict__ keys1,
                                                       ull* __restrict__ keys2) {
    const int tid  = threadIdx.x;
    const int lane = tid & 63;
    const int w    = tid >> 6;
    const int tx   = lane & 15;
    const int quad = (lane >> 4) & 3;

    const int qb0 = blockIdx.x * 128 + w * 32;   // wave's first q-row
    const int sg0 = blockIdx.y * SLICE_G;        // slice's first n-group

    // A-frags: 2 strips x 8 chunks, resident all kernel (64 VGPRs)
    half8 aq[2][8];
#pragma unroll
    for (int mt = 0; mt < 2; ++mt)
#pragma unroll
        for (int c = 0; c < 8; ++c)
            aq[mt][c] = *(const half8*)(qf + ((size_t)((qb0 >> 4) + mt) * 8 + c) * 512 + lane * 8);

    float best_s[8];
    int   best_g[8];
#pragma unroll
    for (int i = 0; i < 8; ++i) { best_s[i] = 3.4e38f; best_g[i] = 0; }

    const short* bp = vf + ((size_t)sg0 * 8) * 512 + lane * 8;
    const float* vp = vsq + sg0 * 16 + tx;

    half8 bA[8], bB[8];
    float vA, vB;

    auto loadg = [&](half8* b, float& vs, int g) {
        const short* p = bp + (size_t)g * 4096;
#pragma unroll
        for (int c = 0; c < 8; ++c) b[c] = *(const half8*)(p + c * 512);
        vs = vp[g * 16];
    };
    auto compute = [&](const half8* b, float vsqr, int g) {
        f32x4 acc[2][2];   // [strip][chunk-parity] -> 4 independent MFMA chains of 4
#pragma unroll
        for (int i = 0; i < 2; ++i) {
            acc[i][0] = (f32x4){0.f, 0.f, 0.f, 0.f};
            acc[i][1] = (f32x4){0.f, 0.f, 0.f, 0.f};
        }
#pragma unroll
        for (int c = 0; c < 8; ++c) {
            acc[0][c & 1] = __builtin_amdgcn_mfma_f32_16x16x32_f16(aq[0][c], b[c], acc[0][c & 1], 0, 0, 0);
            acc[1][c & 1] = __builtin_amdgcn_mfma_f32_16x16x32_f16(aq[1][c], b[c], acc[1][c & 1], 0, 0, 0);
        }
#pragma unroll
        for (int mt = 0; mt < 2; ++mt)
#pragma unroll
            for (int r = 0; r < 4; ++r) {
                const float sc = fmaf(-2.f, acc[mt][0][r], fmaf(-2.f, acc[mt][1][r], vsqr));
                const int s = mt * 4 + r;
                if (sc < best_s[s]) { best_s[s] = sc; best_g[s] = g; }
            }
    };

    // software pipeline: ping-pong, loads for g+1 in flight during compute of g
    loadg(bA, vA, 0);
    for (int g = 0; g < SLICE_G - 2; g += 2) {
        loadg(bB, vB, g + 1);
        compute(bA, vA, g);
        loadg(bA, vA, g + 2);
        compute(bB, vB, g + 1);
    }
    loadg(bB, vB, SLICE_G - 1);
    compute(bA, vA, SLICE_G - 2);
    compute(bB, vB, SLICE_G - 1);

    // Final: per slot, pack (score, n) key, reduce across the 16 tx lanes, insert top-2.
#pragma unroll
    for (int mt = 0; mt < 2; ++mt)
#pragma unroll
        for (int r = 0; r < 4; ++r) {
            const int s = mt * 4 + r;
            const unsigned n = (unsigned)((sg0 + best_g[s]) * 16 + tx);
            ull key = pack_key(best_s[s], n);
#pragma unroll
            for (int off = 8; off; off >>= 1) {
                const ull o = shfl_xor_u64_w16(key, off);
                key = key < o ? key : o;
            }
            if (tx == 0) {
                const int row = qb0 + mt * 16 + quad * 4 + r;
                const ull old = atomicMin(&keys1[row], key);
                const ull loser = (key < old) ? old : key;
                if (loser != ~0ull) atomicMin(&keys2[row], loser);
            }
        }
}

// ---------------- Kernel C: exact fp32 rescore of approx top-2 ----------------
__global__ __launch_bounds__(256) void rescore_kernel(const float* __restrict__ q,
                                                      const float* __restrict__ v,
                                                      const ull* __restrict__ keys1,
                                                      const ull* __restrict__ keys2,
                                                      int* __restrict__ out) {
    const int qi   = blockIdx.x * 4 + (threadIdx.x >> 6);
    const int lane = threadIdx.x & 63;
    const float4 qv = *(const float4*)(q + (size_t)qi * D + lane * 4);
    ull best = ~0ull;
    ull cand[2];
    cand[0] = keys1[qi];
    cand[1] = keys2[qi];
#pragma unroll
    for (int c = 0; c < 2; ++c) {
        if (cand[c] == ~0ull) continue;
        const unsigned idx = (unsigned)cand[c];
        const float4 vv = *(const float4*)(v + (size_t)idx * D + lane * 4);
        float s1 = vv.x * vv.x + vv.y * vv.y + vv.z * vv.z + vv.w * vv.w;   // ||v||^2
        float s2 = qv.x * vv.x + qv.y * vv.y + qv.z * vv.z + qv.w * vv.w;   // q.v
#pragma unroll
        for (int off = 32; off; off >>= 1) {
            s1 += __shfl_xor(s1, off, 64);
            s2 += __shfl_xor(s2, off, 64);
        }
        const float dist = fmaf(-2.0f, s2, s1);
        const ull key = pack_key(dist, idx);
        best = best < key ? best : key;
    }
    if (lane == 0) out[qi] = (int)(unsigned)(best & 0xFFFFFFFFull);
}

extern "C" void kernel_launch(void* const* d_in, const int* in_sizes, int n_in,
                              void* d_out, int out_size, void* d_ws, size_t ws_size,
                              hipStream_t stream) {
    const float* q = (const float*)d_in[0];
    const float* v = (const float*)d_in[1];
    int* out = (int*)d_out;

    char* ws = (char*)d_ws;
    float* vsq = (float*)ws;                 ws += (size_t)N * sizeof(float);
    float* qsq = (float*)ws;                 ws += (size_t)M * sizeof(float);   // unused scratch
    ull* keys1 = (ull*)ws;                   ws += (size_t)2 * M * sizeof(ull);
    ull* keys2 = keys1 + M;
    short* qf = (short*)ws;                  ws += (size_t)M * D * 2;           // 1 MB frag-linear
    short* vf = (short*)ws;                                                    // 64 MB frag-linear

    convert_swz<<<N / 16, 256, 0, stream>>>(v, vf, vsq, nullptr);
    convert_swz<<<M / 16, 256, 0, stream>>>(q, qf, qsq, keys1);

    dim3 grid(M / 128, NSLICE);   // (16, 64): x fastest -> a slice's readers co-dispatch
    dist_argmin_reg<<<grid, 256, 0, stream>>>(qf, vf, vsq, keys1, keys2);

    rescore_kernel<<<M / 4, 256, 0, stream>>>(q, v, keys1, keys2, out);
}

// Round 7
// 355.150 us; speedup vs baseline: 1.5917x; 1.0326x over previous
//
#include <hip/hip_runtime.h>
#include <hip/hip_bf16.h>

#define M 2048
#define N 131072
#define D 256

#define SLICE_G 64                     // n-groups (of 16) per slice = 1024 n = 512 KB f16
#define NSLICE  (N / (SLICE_G * 16))   // 128
#define BIAS    1024.0f                // score = vsq+BIAS-2qv > 0 always -> uint-sortable bits

typedef __attribute__((ext_vector_type(8))) _Float16 half8;  // 8 f16 (4 VGPRs)
typedef __attribute__((ext_vector_type(8))) short short8;
typedef __attribute__((ext_vector_type(4))) float f32x4;     // MFMA acc
typedef unsigned long long ull;

__device__ __forceinline__ ull pack_key(float score, unsigned idx) {
    unsigned u = __float_as_uint(score);
    u = (u & 0x80000000u) ? ~u : (u | 0x80000000u);   // monotonic total order
    return ((ull)u << 32) | idx;
}

// ---------------- Kernel A (fused): V and Q -> f16 FRAGMENT-LINEAR (+ biased vsq, keys) ----
// Frag-linear: row-group g, chunk c (k=c*32..31) -> 1KB tile at xf[(g*8+c)*512];
// lane l=quad*16+tx holds row g*16+tx, k=c*32+quad*8..+7 (MFMA A/B frag order).
__global__ __launch_bounds__(256) void convert_fused(const float* __restrict__ v,
                                                     const float* __restrict__ q,
                                                     short* __restrict__ vf,
                                                     short* __restrict__ qf,
                                                     float* __restrict__ vsqb,
                                                     ull* __restrict__ keys) {
    __shared__ float part[4][16];
    const int b    = blockIdx.x;
    const bool isV = (b < N / 16);
    const int g    = isV ? b : (b - N / 16);
    const float* x = isV ? v : q;
    short* xf      = isV ? vf : qf;

    const int t    = threadIdx.x;
    const int w    = t >> 6;
    const int l    = t & 63;
    const int quad = (t >> 4) & 3;
    const int tx   = t & 15;

    float s = 0.f;
#pragma unroll
    for (int h = 0; h < 2; ++h) {
        const int c = w + h * 4;
        const float* src = x + (size_t)(g * 16 + tx) * D + c * 32 + quad * 8;
        float tmp[8] __attribute__((aligned(16)));
        *(float4*)&tmp[0] = *(const float4*)src;
        *(float4*)&tmp[4] = *(const float4*)(src + 4);
        half8 hh;
#pragma unroll
        for (int e = 0; e < 8; ++e) {
            hh[e] = (_Float16)tmp[e];
            s += tmp[e] * tmp[e];
        }
        *(short8*)(xf + ((size_t)g * 8 + c) * 512 + l * 8) = *(short8*)&hh;
    }
    if (isV) {
        s += __shfl_xor(s, 16, 64);
        s += __shfl_xor(s, 32, 64);
        if (l < 16) part[w][l] = s;
        __syncthreads();
        if (t < 16) vsqb[g * 16 + t] = part[0][t] + part[1][t] + part[2][t] + part[3][t] + BIAS;
    } else if (g == 0) {
        for (int i = t; i < 2 * M; i += 256) keys[i] = ~0ull;
    }
}

// ---------------- Kernel B: register-resident f16 MFMA, barrier/LDS-free main loop -------
// Wave owns 32 q-rows (A-frags resident). Streams one 512KB n-slice frag-linear with
// ping-pong prefetch; per-slot running min over biased-uint keys (score_bits&~63)|g.
__global__ __launch_bounds__(256) void dist_argmin_reg(const short* __restrict__ qf,
                                                       const short* __restrict__ vf,
                                                       const float* __restrict__ vsqb,
                                                       ull* __restrict__ keys1,
                                                       ull* __restrict__ keys2) {
    const int tid  = threadIdx.x;
    const int lane = tid & 63;
    const int w    = tid >> 6;
    const int tx   = lane & 15;
    const int quad = (lane >> 4) & 3;

    // XCD swizzle: lb%8 = XCD (dispatch heuristic); each XCD covers its own 16 slices
    const int lb    = blockIdx.x;           // 2048 blocks
    const int xcd   = lb & 7;
    const int s_    = lb >> 3;              // 0..255 within XCD
    const int slice = xcd * (NSLICE / 8) + (s_ >> 4);
    const int qblk  = s_ & 15;

    const int qb0 = qblk * 128 + w * 32;    // wave's first q-row
    const int sg0 = slice * SLICE_G;        // slice's first n-group

    // A-frags: 2 strips x 8 chunks, resident all kernel (64 VGPRs)
    half8 aq[2][8];
#pragma unroll
    for (int mt = 0; mt < 2; ++mt)
#pragma unroll
        for (int c = 0; c < 8; ++c)
            aq[mt][c] = *(const half8*)(qf + ((size_t)((qb0 >> 4) + mt) * 8 + c) * 512 + lane * 8);

    unsigned best[8];
#pragma unroll
    for (int i = 0; i < 8; ++i) best[i] = 0xFFFFFFFFu;

    const short* bp = vf + ((size_t)sg0 * 8) * 512 + lane * 8;
    const float* vp = vsqb + sg0 * 16 + tx;

    half8 bA[8], bB[8];
    float vA, vB;

    auto loadg = [&](half8* b, float& vs, int g) {
        const short* p = bp + (size_t)g * 4096;
#pragma unroll
        for (int c = 0; c < 8; ++c) b[c] = *(const half8*)(p + c * 512);
        vs = vp[g * 16];
    };
    auto compute = [&](const half8* b, float vsqr, int g) {
        f32x4 acc[2][2];   // 4 independent MFMA chains of 4
#pragma unroll
        for (int i = 0; i < 2; ++i) {
            acc[i][0] = (f32x4){0.f, 0.f, 0.f, 0.f};
            acc[i][1] = (f32x4){0.f, 0.f, 0.f, 0.f};
        }
#pragma unroll
        for (int c = 0; c < 8; ++c) {
            acc[0][c & 1] = __builtin_amdgcn_mfma_f32_16x16x32_f16(aq[0][c], b[c], acc[0][c & 1], 0, 0, 0);
            acc[1][c & 1] = __builtin_amdgcn_mfma_f32_16x16x32_f16(aq[1][c], b[c], acc[1][c & 1], 0, 0, 0);
        }
#pragma unroll
        for (int mt = 0; mt < 2; ++mt)
#pragma unroll
            for (int r = 0; r < 4; ++r) {
                // biased score > 0 -> IEEE bits uint-monotone; pack 6-bit g in LSBs
                const float sc = fmaf(-2.f, acc[mt][0][r], fmaf(-2.f, acc[mt][1][r], vsqr));
                const unsigned key = (__float_as_uint(sc) & 0xFFFFFFC0u) | (unsigned)g;
                const int sl = mt * 4 + r;
                best[sl] = key < best[sl] ? key : best[sl];
            }
    };

    loadg(bA, vA, 0);
    for (int g = 0; g < SLICE_G - 2; g += 2) {
        loadg(bB, vB, g + 1);
        compute(bA, vA, g);
        loadg(bA, vA, g + 2);
        compute(bB, vB, g + 1);
    }
    loadg(bB, vB, SLICE_G - 1);
    compute(bA, vA, SLICE_G - 2);
    compute(bB, vB, SLICE_G - 1);

    // Epilogue: per slot, min across 16 tx lanes; recover winner (g, tx); top-2 insert.
#pragma unroll
    for (int mt = 0; mt < 2; ++mt)
#pragma unroll
        for (int r = 0; r < 4; ++r) {
            const int sl = mt * 4 + r;
            unsigned k = best[sl];
#pragma unroll
            for (int off = 8; off; off >>= 1) {
                const unsigned o = (unsigned)__shfl_xor((int)k, off, 16);
                k = o < k ? o : k;
            }
            const ull bal = __ballot(best[sl] == k);
            const unsigned grp = (unsigned)((bal >> (quad * 16)) & 0xFFFFull);
            const int wtx = __ffs((int)grp) - 1;
            const unsigned n = (unsigned)((sg0 + (int)(k & 63u)) * 16 + wtx);
            if (tx == 0) {
                const int row = qb0 + mt * 16 + quad * 4 + r;
                const ull key64 = ((ull)k << 32) | n;
                const ull old = atomicMin(&keys1[row], key64);
                const ull loser = (key64 < old) ? old : key64;
                if (loser != ~0ull) atomicMin(&keys2[row], loser);
            }
        }
}

// ---------------- Kernel C: exact fp32 rescore of approx top-2 ----------------
__global__ __launch_bounds__(256) void rescore_kernel(const float* __restrict__ q,
                                                      const float* __restrict__ v,
                                                      const ull* __restrict__ keys1,
                                                      const ull* __restrict__ keys2,
                                                      int* __restrict__ out) {
    const int qi   = blockIdx.x * 4 + (threadIdx.x >> 6);
    const int lane = threadIdx.x & 63;
    const float4 qv = *(const float4*)(q + (size_t)qi * D + lane * 4);
    ull best = ~0ull;
    ull cand[2];
    cand[0] = keys1[qi];
    cand[1] = keys2[qi];
#pragma unroll
    for (int c = 0; c < 2; ++c) {
        if (cand[c] == ~0ull) continue;
        const unsigned idx = (unsigned)cand[c];
        const float4 vv = *(const float4*)(v + (size_t)idx * D + lane * 4);
        float s1 = vv.x * vv.x + vv.y * vv.y + vv.z * vv.z + vv.w * vv.w;   // ||v||^2
        float s2 = qv.x * vv.x + qv.y * vv.y + qv.z * vv.z + qv.w * vv.w;   // q.v
#pragma unroll
        for (int off = 32; off; off >>= 1) {
            s1 += __shfl_xor(s1, off, 64);
            s2 += __shfl_xor(s2, off, 64);
        }
        const float dist = fmaf(-2.0f, s2, s1);   // exact fp32 score (sans ||q||^2)
        const ull key = pack_key(dist, idx);
        best = best < key ? best : key;
    }
    if (lane == 0) out[qi] = (int)(unsigned)(best & 0xFFFFFFFFull);
}

extern "C" void kernel_launch(void* const* d_in, const int* in_sizes, int n_in,
                              void* d_out, int out_size, void* d_ws, size_t ws_size,
                              hipStream_t stream) {
    const float* q = (const float*)d_in[0];
    const float* v = (const float*)d_in[1];
    int* out = (int*)d_out;

    char* ws = (char*)d_ws;
    float* vsqb = (float*)ws;                ws += (size_t)N * sizeof(float);   // biased ||v||^2
    ull* keys1 = (ull*)ws;                   ws += (size_t)2 * M * sizeof(ull);
    ull* keys2 = keys1 + M;
    short* qf = (short*)ws;                  ws += (size_t)M * D * 2;           // 1 MB frag-linear
    short* vf = (short*)ws;                                                    // 64 MB frag-linear

    convert_fused<<<N / 16 + M / 16, 256, 0, stream>>>(v, q, vf, qf, vsqb, keys1);

    dist_argmin_reg<<<16 * NSLICE, 256, 0, stream>>>(qf, vf, vsqb, keys1, keys2);

    rescore_kernel<<<M / 4, 256, 0, stream>>>(q, v, keys1, keys2, out);
}

// Round 8
// 321.527 us; speedup vs baseline: 1.7582x; 1.1046x over previous
//
#include <hip/hip_runtime.h>
#include <hip/hip_bf16.h>

#define M 2048
#define N 131072
#define D 256

#define SLICE_G 64                     // n-groups (of 16) per slice = 1024 n = 512 KB f16
#define NSLICE  (N / (SLICE_G * 16))   // 128
#define BIAS    1024.0f                // score = vsq+BIAS-2qv > 0 -> uint-sortable bits

typedef __attribute__((ext_vector_type(8))) _Float16 half8;  // 8 f16 (4 VGPRs)
typedef __attribute__((ext_vector_type(8))) short short8;
typedef __attribute__((ext_vector_type(4))) float f32x4;     // MFMA acc
typedef unsigned long long ull;

__device__ __forceinline__ ull pack_key(float score, unsigned idx) {
    unsigned u = __float_as_uint(score);
    u = (u & 0x80000000u) ? ~u : (u | 0x80000000u);
    return ((ull)u << 32) | idx;
}

// ---------------- Kernel A (fused): V and Q -> f16 FRAGMENT-LINEAR, coalesced ----------
// Frag-linear: row-group g, chunk c (k=c*32..31) -> 1KB tile at xf[(g*8+c)*512];
// lane l=quad*16+tx holds row g*16+tx, k=c*32+quad*8..+7 (MFMA A/B frag order).
// Coalesced read -> LDS (padded fp32) -> frag-order gather -> coalesced write.
__global__ __launch_bounds__(256) void convert_fused(const float* __restrict__ v,
                                                     const float* __restrict__ q,
                                                     short* __restrict__ vf,
                                                     short* __restrict__ qf,
                                                     float* __restrict__ vsqb,
                                                     ull* __restrict__ keys) {
    __shared__ float lds[16 * 260];        // 16 rows x 256 + 4-float pad
    __shared__ float part[4][16];

    const int b    = blockIdx.x;
    const bool isV = (b < N / 16);
    const int g    = isV ? b : (b - N / 16);
    const float* x = isV ? v : q;
    short* xf      = isV ? vf : qf;

    const int t    = threadIdx.x;
    const int w    = t >> 6;
    const int l    = t & 63;
    const int quad = (l >> 4) & 3;
    const int tx   = l & 15;

    // Phase 1: coalesced read of the 16-row group (16 KB), bounce through LDS
    const float* src = x + (size_t)g * 4096;
#pragma unroll
    for (int i = 0; i < 4; ++i) {
        const int fi  = (i * 256 + t) * 4;         // linear float index
        const float4 f = *(const float4*)(src + fi);
        const int row = fi >> 8;
        const int col = fi & 255;
        *(float4*)&lds[row * 260 + col] = f;
    }
    __syncthreads();

    // Phase 2: gather in frag order, convert, coalesced frag-linear write + sumsq
    float s = 0.f;
#pragma unroll
    for (int h = 0; h < 2; ++h) {
        const int c = w + h * 4;
        float tmp[8] __attribute__((aligned(16)));
        *(float4*)&tmp[0] = *(const float4*)&lds[tx * 260 + c * 32 + quad * 8];
        *(float4*)&tmp[4] = *(const float4*)&lds[tx * 260 + c * 32 + quad * 8 + 4];
        half8 hh;
#pragma unroll
        for (int e = 0; e < 8; ++e) {
            hh[e] = (_Float16)tmp[e];
            s += tmp[e] * tmp[e];
        }
        *(short8*)(xf + ((size_t)g * 8 + c) * 512 + l * 8) = *(short8*)&hh;
    }

    if (isV) {
        s += __shfl_xor(s, 16, 64);
        s += __shfl_xor(s, 32, 64);
        if (l < 16) part[w][l] = s;
        __syncthreads();
        if (t < 16) vsqb[g * 16 + t] = part[0][t] + part[1][t] + part[2][t] + part[3][t] + BIAS;
    } else if (g == 0) {
        for (int i = t; i < 2 * M; i += 256) keys[i] = ~0ull;
    }
}

// ---------------- Kernel B: 64 q-rows/wave, register-resident, barrier/LDS-free --------
// A-frags (4 strips x 8 chunks = 128 VGPRs) resident; streams one 512KB n-slice with
// ping-pong B prefetch; per-slot running min over biased-uint keys (bits&~63)|g.
// 64 rows/wave halves VMEM bytes per MFMA vs 32 rows (V traffic 4GB -> 2GB).
__global__ __launch_bounds__(256, 2) void dist_argmin_reg(const short* __restrict__ qf,
                                                          const short* __restrict__ vf,
                                                          const float* __restrict__ vsqb,
                                                          ull* __restrict__ keys1,
                                                          ull* __restrict__ keys2) {
    const int tid  = threadIdx.x;
    const int lane = tid & 63;
    const int w    = tid >> 6;
    const int tx   = lane & 15;
    const int quad = (lane >> 4) & 3;

    // XCD swizzle: 1024 blocks; lb%8 = XCD; each XCD covers its own 16 slices (8 MB)
    const int lb    = blockIdx.x;
    const int xcd   = lb & 7;
    const int s_    = lb >> 3;              // 0..127 within XCD
    const int slice = xcd * 16 + (s_ >> 3);
    const int qblk  = s_ & 7;

    const int qb0 = qblk * 256 + w * 64;    // wave's first q-row (64 rows)
    const int sg0 = slice * SLICE_G;

    half8 aq[4][8];                         // 128 VGPRs, loaded once
#pragma unroll
    for (int mt = 0; mt < 4; ++mt)
#pragma unroll
        for (int c = 0; c < 8; ++c)
            aq[mt][c] = *(const half8*)(qf + ((size_t)((qb0 >> 4) + mt) * 8 + c) * 512 + lane * 8);

    unsigned best[16];
#pragma unroll
    for (int i = 0; i < 16; ++i) best[i] = 0xFFFFFFFFu;

    const short* bp = vf + ((size_t)sg0 * 8) * 512 + lane * 8;
    const float* vp = vsqb + sg0 * 16 + tx;

    half8 bA[8], bB[8];
    float vA, vB;

    auto loadg = [&](half8* b, float& vs, int g) {
        const short* p = bp + (size_t)g * 4096;
#pragma unroll
        for (int c = 0; c < 8; ++c) b[c] = *(const half8*)(p + c * 512);
        vs = vp[g * 16];
    };
    auto compute = [&](const half8* b, float vsqr, int g) {
        f32x4 acc[4];                        // 1 chain per strip; 4-way ILP feeds the pipe
#pragma unroll
        for (int i = 0; i < 4; ++i) acc[i] = (f32x4){0.f, 0.f, 0.f, 0.f};
#pragma unroll
        for (int c = 0; c < 8; ++c)
#pragma unroll
            for (int mt = 0; mt < 4; ++mt)
                acc[mt] = __builtin_amdgcn_mfma_f32_16x16x32_f16(aq[mt][c], b[c], acc[mt], 0, 0, 0);
#pragma unroll
        for (int mt = 0; mt < 4; ++mt)
#pragma unroll
            for (int r = 0; r < 4; ++r) {
                const float sc = fmaf(-2.f, acc[mt][r], vsqr);
                const unsigned key = (__float_as_uint(sc) & 0xFFFFFFC0u) | (unsigned)g;
                const int sl = mt * 4 + r;
                best[sl] = key < best[sl] ? key : best[sl];
            }
    };

    loadg(bA, vA, 0);
    for (int g = 0; g < SLICE_G - 2; g += 2) {
        loadg(bB, vB, g + 1);
        compute(bA, vA, g);
        loadg(bA, vA, g + 2);
        compute(bB, vB, g + 1);
    }
    loadg(bB, vB, SLICE_G - 1);
    compute(bA, vA, SLICE_G - 2);
    compute(bB, vB, SLICE_G - 1);

    // Epilogue: per slot, min across 16 tx lanes; recover (g, tx); top-2 insert.
#pragma unroll
    for (int mt = 0; mt < 4; ++mt)
#pragma unroll
        for (int r = 0; r < 4; ++r) {
            const int sl = mt * 4 + r;
            unsigned k = best[sl];
#pragma unroll
            for (int off = 8; off; off >>= 1) {
                const unsigned o = (unsigned)__shfl_xor((int)k, off, 16);
                k = o < k ? o : k;
            }
            const ull bal = __ballot(best[sl] == k);
            const unsigned grp = (unsigned)((bal >> (quad * 16)) & 0xFFFFull);
            const int wtx = __ffs((int)grp) - 1;
            const unsigned n = (unsigned)((sg0 + (int)(k & 63u)) * 16 + wtx);
            if (tx == 0) {
                const int row = qb0 + mt * 16 + quad * 4 + r;
                const ull key64 = ((ull)k << 32) | n;
                const ull old = atomicMin(&keys1[row], key64);
                const ull loser = (key64 < old) ? old : key64;
                if (loser != ~0ull) atomicMin(&keys2[row], loser);
            }
        }
}

// ---------------- Kernel C: exact fp32 rescore of approx top-2 ----------------
__global__ __launch_bounds__(256) void rescore_kernel(const float* __restrict__ q,
                                                      const float* __restrict__ v,
                                                      const ull* __restrict__ keys1,
                                                      const ull* __restrict__ keys2,
                                                      int* __restrict__ out) {
    const int qi   = blockIdx.x * 4 + (threadIdx.x >> 6);
    const int lane = threadIdx.x & 63;
    const float4 qv = *(const float4*)(q + (size_t)qi * D + lane * 4);
    ull best = ~0ull;
    ull cand[2];
    cand[0] = keys1[qi];
    cand[1] = keys2[qi];
#pragma unroll
    for (int c = 0; c < 2; ++c) {
        if (cand[c] == ~0ull) continue;
        const unsigned idx = (unsigned)cand[c];
        const float4 vv = *(const float4*)(v + (size_t)idx * D + lane * 4);
        float s1 = vv.x * vv.x + vv.y * vv.y + vv.z * vv.z + vv.w * vv.w;   // ||v||^2
        float s2 = qv.x * vv.x + qv.y * vv.y + qv.z * vv.z + qv.w * vv.w;   // q.v
#pragma unroll
        for (int off = 32; off; off >>= 1) {
            s1 += __shfl_xor(s1, off, 64);
            s2 += __shfl_xor(s2, off, 64);
        }
        const float dist = fmaf(-2.0f, s2, s1);   // exact fp32 (sans ||q||^2)
        const ull key = pack_key(dist, idx);
        best = best < key ? best : key;
    }
    if (lane == 0) out[qi] = (int)(unsigned)(best & 0xFFFFFFFFull);
}

extern "C" void kernel_launch(void* const* d_in, const int* in_sizes, int n_in,
                              void* d_out, int out_size, void* d_ws, size_t ws_size,
                              hipStream_t stream) {
    const float* q = (const float*)d_in[0];
    const float* v = (const float*)d_in[1];
    int* out = (int*)d_out;

    char* ws = (char*)d_ws;
    float* vsqb = (float*)ws;                ws += (size_t)N * sizeof(float);
    ull* keys1 = (ull*)ws;                   ws += (size_t)2 * M * sizeof(ull);
    ull* keys2 = keys1 + M;
    short* qf = (short*)ws;                  ws += (size_t)M * D * 2;
    short* vf = (short*)ws;                  // 64 MB frag-linear

    convert_fused<<<N / 16 + M / 16, 256, 0, stream>>>(v, q, vf, qf, vsqb, keys1);

    dist_argmin_reg<<<(M / 256) * NSLICE, 256, 0, stream>>>(qf, vf, vsqb, keys1, keys2);

    rescore_kernel<<<M / 4, 256, 0, stream>>>(q, v, keys1, keys2, out);
}